// Round 2
// baseline (77.913 us; speedup 1.0000x reference)
//
#include <hip/hip_runtime.h>

// VA forward: out[row, 3j:3j+3] = M(theta_row) @ ((p + t) * (p != 0))
// where M = Rz(th2) * Ry(th0) * Rx(th1), t = th[3:6].
//
// Block = 256 threads, 32 rows (2400 floats = 600 float4) per block.
// Stage conv->LDS as float4; trig ONCE per row (32 lanes) into LDS params;
// in-place transform in LDS (stride-3 float access = 2-way bank alias, free);
// dense float4 writeout. Memory-bound: ~383 MB total traffic.

constexpr int JOINTS          = 25;
constexpr int FLOATS_PER_ROW  = 75;
constexpr int ROWS_PER_BLOCK  = 32;
constexpr int BLOCK           = 256;
constexpr int FLOATS_PER_BLK  = ROWS_PER_BLOCK * FLOATS_PER_ROW;   // 2400
constexpr int VEC4_PER_BLK    = FLOATS_PER_BLK / 4;                // 600
constexpr int TASKS_PER_BLK   = ROWS_PER_BLOCK * JOINTS;           // 800

__global__ __launch_bounds__(BLOCK) void va_kernel(
    const float4* __restrict__ conv4,
    const float*  __restrict__ theta,
    float4*       __restrict__ out4,
    int nrows)
{
    __shared__ float buf[FLOATS_PER_BLK];
    __shared__ float prm[ROWS_PER_BLOCK][12];   // m00..m22, tx, ty, tz

    const int tid = threadIdx.x;
    const size_t row0  = (size_t)blockIdx.x * ROWS_PER_BLOCK;
    const size_t base4 = (size_t)blockIdx.x * VEC4_PER_BLK;
    const size_t total4 = (size_t)nrows * FLOATS_PER_ROW / 4;

    // ---- stage in: 600 float4 per block ----
    #pragma unroll
    for (int i = tid; i < VEC4_PER_BLK; i += BLOCK) {
        size_t g = base4 + i;
        if (g < total4)
            *reinterpret_cast<float4*>(&buf[i * 4]) = conv4[g];
    }

    // ---- per-row params: trig once per row ----
    if (tid < ROWS_PER_BLOCK) {
        size_t row = row0 + tid;
        if (row < (size_t)nrows) {
            const float* th = theta + row * 6;
            float ay = th[0], ax = th[1], az = th[2];
            float tx = th[3], ty = th[4], tz = th[5];

            float sy = __sinf(ay), cy = __cosf(ay);
            float sx = __sinf(ax), cx = __cosf(ax);
            float sz = __sinf(az), cz = __cosf(az);

            // M = Rz(az) * Ry(ay) * Rx(ax)
            prm[tid][0] = cz * cy;
            prm[tid][1] = -sz * cx + cz * sy * sx;
            prm[tid][2] =  sz * sx + cz * sy * cx;
            prm[tid][3] = sz * cy;
            prm[tid][4] =  cz * cx + sz * sy * sx;
            prm[tid][5] = -cz * sx + sz * sy * cx;
            prm[tid][6] = -sy;
            prm[tid][7] = cy * sx;
            prm[tid][8] = cy * cx;
            prm[tid][9]  = tx;
            prm[tid][10] = ty;
            prm[tid][11] = tz;
        }
    }
    __syncthreads();

    // ---- transform in place: task t owns LDS floats 3t..3t+2 ----
    #pragma unroll
    for (int t = tid; t < TASKS_PER_BLK; t += BLOCK) {
        int r = t / JOINTS;                 // magic-mul div
        float* p = &buf[3 * t];
        const float* m = prm[r];

        float x = p[0], y = p[1], z = p[2];
        float qx = (x != 0.0f) ? (x + m[9])  : 0.0f;
        float qy = (y != 0.0f) ? (y + m[10]) : 0.0f;
        float qz = (z != 0.0f) ? (z + m[11]) : 0.0f;

        p[0] = m[0] * qx + m[1] * qy + m[2] * qz;
        p[1] = m[3] * qx + m[4] * qy + m[5] * qz;
        p[2] = m[6] * qx + m[7] * qy + m[8] * qz;
    }
    __syncthreads();

    // ---- stage out: dense float4 ----
    #pragma unroll
    for (int i = tid; i < VEC4_PER_BLK; i += BLOCK) {
        size_t g = base4 + i;
        if (g < total4)
            out4[g] = *reinterpret_cast<const float4*>(&buf[i * 4]);
    }
}

extern "C" void kernel_launch(void* const* d_in, const int* in_sizes, int n_in,
                              void* d_out, int out_size, void* d_ws, size_t ws_size,
                              hipStream_t stream) {
    const float4* conv4 = (const float4*)d_in[0];
    const float*  theta = (const float*)d_in[1];
    float4* out4 = (float4*)d_out;

    int nrows  = out_size / FLOATS_PER_ROW;                    // 614400
    int blocks = (nrows + ROWS_PER_BLOCK - 1) / ROWS_PER_BLOCK; // 19200
    va_kernel<<<blocks, BLOCK, 0, stream>>>(conv4, theta, out4, nrows);
}

// Round 3
// 74.943 us; speedup vs baseline: 1.0396x; 1.0396x over previous
//
#include <hip/hip_runtime.h>

// VA forward: out[row, 3j:3j+3] = M(theta_row) @ ((p + t) * (p != 0))
// where M = Rz(th2) * Ry(th0) * Rx(th1), t = th[3:6].
//
// Half-staged: float4-dense global->LDS for conv; trig once per row (32
// lanes) while staging loads are in flight; ONE barrier; transform reads
// 3 floats from LDS (stride-3 = 2-way bank alias, free) and stores 12B/lane
// directly to global (dense 768B/wave). 614400 rows % 32 == 0 -> no tail.

constexpr int JOINTS          = 25;
constexpr int FLOATS_PER_ROW  = 75;
constexpr int ROWS_PER_BLOCK  = 32;
constexpr int BLOCK           = 256;
constexpr int FLOATS_PER_BLK  = ROWS_PER_BLOCK * FLOATS_PER_ROW;   // 2400
constexpr int VEC4_PER_BLK    = FLOATS_PER_BLK / 4;                // 600
constexpr int TASKS_PER_BLK   = ROWS_PER_BLOCK * JOINTS;           // 800

__global__ __launch_bounds__(BLOCK) void va_kernel(
    const float4* __restrict__ conv4,
    const float*  __restrict__ theta,
    float*        __restrict__ out)
{
    __shared__ float buf[FLOATS_PER_BLK];
    __shared__ float prm[ROWS_PER_BLOCK][12];   // m00..m22, tx, ty, tz

    const int tid = threadIdx.x;
    const size_t row0  = (size_t)blockIdx.x * ROWS_PER_BLOCK;
    const size_t base4 = (size_t)blockIdx.x * VEC4_PER_BLK;

    // ---- theta load first (in flight before staging loop) ----
    float ay, ax, az, tx, ty, tz;
    if (tid < ROWS_PER_BLOCK) {
        const float* th = theta + (row0 + tid) * 6;
        ay = th[0]; ax = th[1]; az = th[2];
        tx = th[3]; ty = th[4]; tz = th[5];
    }

    // ---- stage conv -> LDS, float4 dense (600 per block, no tail) ----
    #pragma unroll
    for (int k = 0; k < 3; ++k) {
        int i = tid + k * BLOCK;
        if (i < VEC4_PER_BLK)
            *reinterpret_cast<float4*>(&buf[i * 4]) = conv4[base4 + i];
    }

    // ---- per-row params: trig once per row ----
    if (tid < ROWS_PER_BLOCK) {
        float sy = __sinf(ay), cy = __cosf(ay);
        float sx = __sinf(ax), cx = __cosf(ax);
        float sz = __sinf(az), cz = __cosf(az);

        // M = Rz(az) * Ry(ay) * Rx(ax)
        prm[tid][0] = cz * cy;
        prm[tid][1] = -sz * cx + cz * sy * sx;
        prm[tid][2] =  sz * sx + cz * sy * cx;
        prm[tid][3] = sz * cy;
        prm[tid][4] =  cz * cx + sz * sy * sx;
        prm[tid][5] = -cz * sx + sz * sy * cx;
        prm[tid][6] = -sy;
        prm[tid][7] = cy * sx;
        prm[tid][8] = cy * cx;
        prm[tid][9]  = tx;
        prm[tid][10] = ty;
        prm[tid][11] = tz;
    }
    __syncthreads();

    // ---- transform from LDS, store direct to global ----
    float* oblk = out + base4 * 4;
    #pragma unroll
    for (int k = 0; k < 4; ++k) {
        int t = tid + k * BLOCK;
        if (t < TASKS_PER_BLK) {
            int r = t / JOINTS;                 // magic-mul div
            const float* p = &buf[3 * t];
            const float* m = prm[r];

            float x = p[0], y = p[1], z = p[2];
            float qx = (x != 0.0f) ? (x + m[9])  : 0.0f;
            float qy = (y != 0.0f) ? (y + m[10]) : 0.0f;
            float qz = (z != 0.0f) ? (z + m[11]) : 0.0f;

            float* o = oblk + 3 * t;
            o[0] = m[0] * qx + m[1] * qy + m[2] * qz;
            o[1] = m[3] * qx + m[4] * qy + m[5] * qz;
            o[2] = m[6] * qx + m[7] * qy + m[8] * qz;
        }
    }
}

extern "C" void kernel_launch(void* const* d_in, const int* in_sizes, int n_in,
                              void* d_out, int out_size, void* d_ws, size_t ws_size,
                              hipStream_t stream) {
    const float4* conv4 = (const float4*)d_in[0];
    const float*  theta = (const float*)d_in[1];
    float* out = (float*)d_out;

    int nrows  = out_size / FLOATS_PER_ROW;                     // 614400
    int blocks = nrows / ROWS_PER_BLOCK;                        // 19200 exact
    va_kernel<<<blocks, BLOCK, 0, stream>>>(conv4, theta, out);
}

// Round 4
// 67.899 us; speedup vs baseline: 1.1475x; 1.1037x over previous
//
#include <hip/hip_runtime.h>

// VA forward: out[row, 3j:3j+3] = M(theta_row) @ ((p + t) * (p != 0))
// where M = Rz(th2) * Ry(th0) * Rx(th1), t = th[3:6].
// One thread per joint (R1 structure — best so far at 71.1us).
// This round's isolated change: non-temporal load/store on the two 184MB
// streams (conv read-once, out write-once) to avoid L2 allocation;
// theta loads stay cached (25x reuse per row).

constexpr int JOINTS = 25;

__global__ __launch_bounds__(256) void va_kernel(
    const float* __restrict__ conv,
    const float* __restrict__ theta,
    float* __restrict__ out,
    int total)   // total = N * JOINTS joint-tasks
{
    int idx = blockIdx.x * 256 + threadIdx.x;
    if (idx >= total) return;

    unsigned row = (unsigned)idx / JOINTS;        // magic-mul div by 25
    unsigned j   = (unsigned)idx - row * JOINTS;

    const float* th = theta + (size_t)row * 6;
    float ay = th[0], ax = th[1], az = th[2];
    float tx = th[3], ty = th[4], tz = th[5];

    float sy = __sinf(ay), cy = __cosf(ay);
    float sx = __sinf(ax), cx = __cosf(ax);
    float sz = __sinf(az), cz = __cosf(az);

    // M = Rz(az) * Ry(ay) * Rx(ax)
    float m00 = cz * cy;
    float m01 = -sz * cx + cz * sy * sx;
    float m02 =  sz * sx + cz * sy * cx;
    float m10 = sz * cy;
    float m11 =  cz * cx + sz * sy * sx;
    float m12 = -cz * sx + sz * sy * cx;
    float m20 = -sy;
    float m21 = cy * sx;
    float m22 = cy * cx;

    const float* p = conv + (size_t)row * 75 + j * 3;
    float x = __builtin_nontemporal_load(p + 0);
    float y = __builtin_nontemporal_load(p + 1);
    float z = __builtin_nontemporal_load(p + 2);

    float qx = (x != 0.0f) ? (x + tx) : 0.0f;
    float qy = (y != 0.0f) ? (y + ty) : 0.0f;
    float qz = (z != 0.0f) ? (z + tz) : 0.0f;

    float ox = m00 * qx + m01 * qy + m02 * qz;
    float oy = m10 * qx + m11 * qy + m12 * qz;
    float oz = m20 * qx + m21 * qy + m22 * qz;

    float* o = out + (size_t)row * 75 + j * 3;
    __builtin_nontemporal_store(ox, o + 0);
    __builtin_nontemporal_store(oy, o + 1);
    __builtin_nontemporal_store(oz, o + 2);
}

extern "C" void kernel_launch(void* const* d_in, const int* in_sizes, int n_in,
                              void* d_out, int out_size, void* d_ws, size_t ws_size,
                              hipStream_t stream) {
    const float* conv  = (const float*)d_in[0];
    const float* theta = (const float*)d_in[1];
    float* out = (float*)d_out;

    int total = out_size / 3;                 // N * 25 joint tasks
    int blocks = (total + 255) / 256;
    va_kernel<<<blocks, 256, 0, stream>>>(conv, theta, out, total);
}